// Round 5
// baseline (459.828 us; speedup 1.0000x reference)
//
#include <hip/hip_runtime.h>
#include <math.h>

#define NN 16384
#define KK 16

typedef float f32x4 __attribute__((ext_vector_type(4)));

// ---------- kernel 1: pure zero-fill of the 1 GiB adjacency ----------
// Contiguous, fully-coalesced float4 streaming stores (rocclr-fill shape).
#define FILL_BLOCKS 2048
__global__ __launch_bounds__(256) void fill_zero(f32x4* __restrict__ out) {
    const int tid = blockIdx.x * 256 + threadIdx.x;
    const int nthreads = FILL_BLOCKS * 256;
    const f32x4 z4 = {0.f, 0.f, 0.f, 0.f};
    // (NN*NN/4) float4s / nthreads = 128 iterations exactly
#pragma unroll 4
    for (int k = 0; k < (NN * (NN / 4)) / nthreads; ++k)
        __builtin_nontemporal_store(z4, out + (size_t)k * nthreads + tid);
}

// ---------- kernel 2: pack nodes into SoA float4 {x,y,z,sq} ----------
__global__ void prep_kernel(const float* __restrict__ nodes,
                            float4* __restrict__ pts) {
#pragma clang fp contract(off)
    const int i = blockIdx.x * blockDim.x + threadIdx.x;
    if (i < NN) {
        const float x = nodes[3 * i + 0];
        const float y = nodes[3 * i + 1];
        const float z = nodes[3 * i + 2];
        pts[i] = make_float4(x, y, z, (x * x + y * y) + z * z);
    }
}

// Verified distributed-sorted-list insert (identical machinery to r1-r3).
__device__ __forceinline__ bool lexless(float da, int ia, float db, int ib) {
    return (da < db) || ((da == db) && (ia < ib));
}

__device__ __forceinline__ void insert_tile(bool rough, float d2, int j,
                                            float& ld, int& li,
                                            float& td, int& ti, float& td2u,
                                            int lane) {
#pragma clang fp contract(off)
    if (!__any(rough)) return;
    float dist = INFINITY;
    if (rough) dist = sqrtf(fmaxf(d2, 0.0f));   // IEEE sqrt, matches reference
    bool done = false;
    while (true) {
        const bool pass = (!done) && rough && lexless(dist, j, td, ti);
        const unsigned long long m = __ballot(pass);
        if (m == 0ull) break;
        const int src = __ffsll(m) - 1;
        const float dc = __shfl(dist, src);
        const int   ic = __shfl(j, src);
        if (lane == src) done = true;
        const bool gt = lexless(dc, ic, ld, li);
        const unsigned long long gm = __ballot(gt);
        const int p = __ffsll(gm) - 1;
        const float pd = __shfl_up(ld, 1);
        const int   pi = __shfl_up(li, 1);
        if (gt) {
            if (lane == p) { ld = dc; li = ic; }
            else           { ld = pd; li = pi; }
        }
        td = __shfl(ld, 16);
        ti = __shfl(li, 16);
        td2u = td * td * 1.000001f;   // conservative d2-domain screen bound
    }
}

// ---------- kernel 3: KNN scan (store-free loop) + write the 16 ones ----------
// One wave per row; 256 candidates (4 float4 tiles) per iteration, 1-deep
// prefetch, one merged min-screen ballot per iteration.
__global__ __launch_bounds__(256) void knn_ones_kernel(
        const float4* __restrict__ pts, float* __restrict__ out) {
#pragma clang fp contract(off)
    const int lane = threadIdx.x & 63;
    const int wave = threadIdx.x >> 6;
    const int row  = blockIdx.x * 4 + wave;

    const float4 p = pts[row];
    const float xi = p.x, yi = p.y, zi = p.z, sqi = p.w;

    float ld = INFINITY; int li = 0x7fffffff;   // my list slot (lanes 0..16)
    float td = INFINITY; int ti = 0x7fffffff;   // lane-16 (worst kept)
    float td2u = INFINITY;

    float4 q0 = pts[lane];
    float4 q1 = pts[64 + lane];
    float4 q2 = pts[128 + lane];
    float4 q3 = pts[192 + lane];

    for (int t = 0; t < NN / 256; ++t) {
        const int base = t * 256;
        const int nxt = (t + 1 < NN / 256) ? base + 256 : base;
        const float4 n0 = pts[nxt + lane];
        const float4 n1 = pts[nxt + 64 + lane];
        const float4 n2 = pts[nxt + 128 + lane];
        const float4 n3 = pts[nxt + 192 + lane];

        // Reference arithmetic: fma-chain dot, un-contracted d2.
        const float dot0 = fmaf(zi, q0.z, fmaf(yi, q0.y, xi * q0.x));
        const float d20  = (sqi + q0.w) - 2.0f * dot0;
        const float dot1 = fmaf(zi, q1.z, fmaf(yi, q1.y, xi * q1.x));
        const float d21  = (sqi + q1.w) - 2.0f * dot1;
        const float dot2 = fmaf(zi, q2.z, fmaf(yi, q2.y, xi * q2.x));
        const float d22  = (sqi + q2.w) - 2.0f * dot2;
        const float dot3 = fmaf(zi, q3.z, fmaf(yi, q3.y, xi * q3.x));
        const float d23  = (sqi + q3.w) - 2.0f * dot3;

        const float mn = fminf(fminf(d20, d21), fminf(d22, d23));
        if (__any(mn <= td2u)) {
            // Screens tighten tile-to-tile; still a conservative superset of
            // the exact lex re-check inside insert_tile, so order-correct.
            insert_tile(d20 <= td2u, d20, base + lane,       ld, li, td, ti, td2u, lane);
            insert_tile(d21 <= td2u, d21, base + 64 + lane,  ld, li, td, ti, td2u, lane);
            insert_tile(d22 <= td2u, d22, base + 128 + lane, ld, li, td, ti, td2u, lane);
            insert_tile(d23 <= td2u, d23, base + 192 + lane, ld, li, td, ti, td2u, lane);
        }
        q0 = n0; q1 = n1; q2 = n2; q3 = n3;
    }

    // Fill kernel already zeroed the row (prior dispatch on this stream);
    // lanes 1..16 hold the K neighbors in sorted order — write the ones.
    if (lane >= 1 && lane <= KK)
        out[(size_t)row * NN + li] = 1.0f;
}

extern "C" void kernel_launch(void* const* d_in, const int* in_sizes, int n_in,
                              void* d_out, int out_size, void* d_ws, size_t ws_size,
                              hipStream_t stream) {
    const float* nodes = (const float*)d_in[0];
    float* out = (float*)d_out;
    (void)in_sizes; (void)n_in; (void)out_size; (void)ws_size;
    float4* pts = (float4*)d_ws;    // 256 KB scratch

    hipLaunchKernelGGL(prep_kernel, dim3(NN / 256), dim3(256), 0, stream,
                       nodes, pts);
    hipLaunchKernelGGL(fill_zero, dim3(FILL_BLOCKS), dim3(256), 0, stream,
                       (f32x4*)out);
    hipLaunchKernelGGL(knn_ones_kernel, dim3(NN / 4), dim3(256), 0, stream,
                       pts, out);
}

// Round 6
// 359.609 us; speedup vs baseline: 1.2787x; 1.2787x over previous
//
#include <hip/hip_runtime.h>
#include <math.h>

#define NN 16384
#define KK 16
#define RPW 2                       // rows per scan wave
#define SCAN_WAVES 4
#define RPB (SCAN_WAVES * RPW)      // 8 rows per block

typedef float f32x4 __attribute__((ext_vector_type(4)));

// ---------- pack nodes into SoA float4 {x,y,z,sq} (reference arithmetic) ----
__global__ void prep_kernel(const float* __restrict__ nodes,
                            float4* __restrict__ pts) {
#pragma clang fp contract(off)
    const int i = blockIdx.x * blockDim.x + threadIdx.x;
    if (i < NN) {
        const float x = nodes[3 * i + 0];
        const float y = nodes[3 * i + 1];
        const float z = nodes[3 * i + 2];
        pts[i] = make_float4(x, y, z, (x * x + y * y) + z * z);
    }
}

// Verified distributed-sorted-list insert (identical machinery to r1-r5).
__device__ __forceinline__ bool lexless(float da, int ia, float db, int ib) {
    return (da < db) || ((da == db) && (ia < ib));
}

__device__ __forceinline__ void insert_tile(bool rough, float d2, int j,
                                            float& ld, int& li,
                                            float& td, int& ti, float& td2u,
                                            int lane) {
#pragma clang fp contract(off)
    if (!__any(rough)) return;
    float dist = INFINITY;
    if (rough) dist = sqrtf(fmaxf(d2, 0.0f));   // IEEE sqrt, matches reference
    bool done = false;
    while (true) {
        const bool pass = (!done) && rough && lexless(dist, j, td, ti);
        const unsigned long long m = __ballot(pass);
        if (m == 0ull) break;
        const int src = __ffsll(m) - 1;
        const float dc = __shfl(dist, src);
        const int   ic = __shfl(j, src);
        if (lane == src) done = true;
        const bool gt = lexless(dc, ic, ld, li);
        const unsigned long long gm = __ballot(gt);
        const int p = __ffsll(gm) - 1;
        const float pd = __shfl_up(ld, 1);
        const int   pi = __shfl_up(li, 1);
        if (gt) {
            if (lane == p) { ld = dc; li = ic; }
            else           { ld = pd; li = pi; }
        }
        td = __shfl(ld, 16);
        ti = __shfl(li, 16);
        td2u = td * td * 1.000001f;   // conservative d2-domain screen bound
    }
}

// ---------- main kernel: 4 scan waves (2 rows each) + 1 zero/ones wave ------
__global__ __launch_bounds__(320) void knn_main(const float4* __restrict__ pts,
                                                float* __restrict__ out) {
#pragma clang fp contract(off)
    const int lane = threadIdx.x & 63;
    const int wid  = threadIdx.x >> 6;
    const int rowBase = blockIdx.x * RPB;
    __shared__ int nb[RPB][16];

    if (wid == SCAN_WAVES) {
        // Zero wave: NT-stream zeros for this block's 8 rows (512 KB).
        f32x4* ob = (f32x4*)(out + (size_t)rowBase * NN);
        const f32x4 z4 = {0.f, 0.f, 0.f, 0.f};
#pragma unroll 8
        for (int k = 0; k < RPB * (NN / 4) / 64; ++k)
            __builtin_nontemporal_store(z4, ob + k * 64 + lane);
        // Drain so this wave's later 1.0 stores are ordered after the zeros.
        asm volatile("s_waitcnt vmcnt(0)" ::: "memory");
    } else {
        const int rowA = rowBase + wid * RPW;
        const float4 pA = pts[rowA];
        const float4 pB = pts[rowA + 1];
        const float xA = pA.x, yA = pA.y, zA = pA.z, sA = pA.w;
        const float xB = pB.x, yB = pB.y, zB = pB.z, sB = pB.w;

        float ldA = INFINITY; int liA = 0x7fffffff;
        float tdA = INFINITY; int tiA = 0x7fffffff; float t2A = INFINITY;
        float ldB = INFINITY; int liB = 0x7fffffff;
        float tdB = INFINITY; int tiB = 0x7fffffff; float t2B = INFINITY;

        float4 q0 = pts[lane];
        float4 q1 = pts[64 + lane];
        float4 q2 = pts[128 + lane];
        float4 q3 = pts[192 + lane];

        for (int t = 0; t < NN / 256; ++t) {
            const int base = t * 256;
            const int nxt = (t + 1 < NN / 256) ? base + 256 : base;
            const float4 n0 = pts[nxt + lane];
            const float4 n1 = pts[nxt + 64 + lane];
            const float4 n2 = pts[nxt + 128 + lane];
            const float4 n3 = pts[nxt + 192 + lane];

            // Reference arithmetic: fma-chain dot, un-contracted d2.
            const float dA0 = (sA + q0.w) - 2.0f * fmaf(zA, q0.z, fmaf(yA, q0.y, xA * q0.x));
            const float dA1 = (sA + q1.w) - 2.0f * fmaf(zA, q1.z, fmaf(yA, q1.y, xA * q1.x));
            const float dA2 = (sA + q2.w) - 2.0f * fmaf(zA, q2.z, fmaf(yA, q2.y, xA * q2.x));
            const float dA3 = (sA + q3.w) - 2.0f * fmaf(zA, q3.z, fmaf(yA, q3.y, xA * q3.x));
            const float dB0 = (sB + q0.w) - 2.0f * fmaf(zB, q0.z, fmaf(yB, q0.y, xB * q0.x));
            const float dB1 = (sB + q1.w) - 2.0f * fmaf(zB, q1.z, fmaf(yB, q1.y, xB * q1.x));
            const float dB2 = (sB + q2.w) - 2.0f * fmaf(zB, q2.z, fmaf(yB, q2.y, xB * q2.x));
            const float dB3 = (sB + q3.w) - 2.0f * fmaf(zB, q3.z, fmaf(yB, q3.y, xB * q3.x));

            const float mnA = fminf(fminf(dA0, dA1), fminf(dA2, dA3));
            const float mnB = fminf(fminf(dB0, dB1), fminf(dB2, dB3));
            if (__any((mnA <= t2A) || (mnB <= t2B))) {
                // Screens tighten call-to-call; each stays a conservative
                // superset of the exact lex re-check inside insert_tile.
                insert_tile(dA0 <= t2A, dA0, base + lane,       ldA, liA, tdA, tiA, t2A, lane);
                insert_tile(dA1 <= t2A, dA1, base + 64 + lane,  ldA, liA, tdA, tiA, t2A, lane);
                insert_tile(dA2 <= t2A, dA2, base + 128 + lane, ldA, liA, tdA, tiA, t2A, lane);
                insert_tile(dA3 <= t2A, dA3, base + 192 + lane, ldA, liA, tdA, tiA, t2A, lane);
                insert_tile(dB0 <= t2B, dB0, base + lane,       ldB, liB, tdB, tiB, t2B, lane);
                insert_tile(dB1 <= t2B, dB1, base + 64 + lane,  ldB, liB, tdB, tiB, t2B, lane);
                insert_tile(dB2 <= t2B, dB2, base + 128 + lane, ldB, liB, tdB, tiB, t2B, lane);
                insert_tile(dB3 <= t2B, dB3, base + 192 + lane, ldB, liB, tdB, tiB, t2B, lane);
            }
            q0 = n0; q1 = n1; q2 = n2; q3 = n3;
        }

        // Deposit neighbor indices (lanes 1..16 hold them in sorted order).
        if (lane >= 1 && lane <= KK) {
            nb[wid * RPW + 0][lane - 1] = liA;
            nb[wid * RPW + 1][lane - 1] = liB;
        }
    }

    __syncthreads();

    // Zero wave writes all 128 ones: same-wave ordering after its vmcnt(0)
    // drain guarantees the 1.0s land after the zeros.
    if (wid == SCAN_WAVES) {
#pragma unroll
        for (int m = lane; m < RPB * 16; m += 64) {
            const int r = m >> 4;
            out[(size_t)(rowBase + r) * NN + nb[r][m & 15]] = 1.0f;
        }
    }
}

extern "C" void kernel_launch(void* const* d_in, const int* in_sizes, int n_in,
                              void* d_out, int out_size, void* d_ws, size_t ws_size,
                              hipStream_t stream) {
    const float* nodes = (const float*)d_in[0];
    float* out = (float*)d_out;
    (void)in_sizes; (void)n_in; (void)out_size; (void)ws_size;
    float4* pts = (float4*)d_ws;    // 256 KB scratch

    hipLaunchKernelGGL(prep_kernel, dim3(NN / 256), dim3(256), 0, stream,
                       nodes, pts);
    hipLaunchKernelGGL(knn_main, dim3(NN / RPB), dim3(320), 0, stream,
                       pts, out);
}